// Round 1
// baseline (1019.129 us; speedup 1.0000x reference)
//
#include <hip/hip_runtime.h>
#include <math.h>

static __device__ __forceinline__ float lrelu(float e) { return e > 0.0f ? e : 0.2f * e; }

// ---------------- CSR build (dst-sorted adjacency, self-loops appended) ----------------
__global__ void count_kernel(const int* __restrict__ dst, int* __restrict__ cnt, int E, int n) {
  int e = blockIdx.x * blockDim.x + threadIdx.x;
  if (e >= E + n) return;
  int d = (e < E) ? dst[e] : (e - E);
  atomicAdd(&cnt[d], 1);
}

__global__ __launch_bounds__(1024) void scan_kernel(const int* __restrict__ counts,
                                                    int* __restrict__ offsets, int n) {
  __shared__ int sh[1024];
  __shared__ int run_s;
  int tid = threadIdx.x;
  if (tid == 0) run_s = 0;
  __syncthreads();
  for (int base = 0; base < n; base += 1024) {
    int i = base + tid;
    int v = (i < n) ? counts[i] : 0;
    sh[tid] = v;
    __syncthreads();
    for (int d = 1; d < 1024; d <<= 1) {
      int t = (tid >= d) ? sh[tid - d] : 0;
      __syncthreads();
      sh[tid] += t;
      __syncthreads();
    }
    int run = run_s;
    if (i < n) offsets[i] = run + sh[tid] - v;  // exclusive
    __syncthreads();
    if (tid == 0) run_s = run + sh[1023];
    __syncthreads();
  }
  if (tid == 0) offsets[n] = run_s;
}

__global__ void copy_kernel(const int* __restrict__ a, int* __restrict__ b, int n) {
  int i = blockIdx.x * blockDim.x + threadIdx.x;
  if (i < n) b[i] = a[i];
}

__global__ void scatter_kernel(const int* __restrict__ src, const int* __restrict__ dst,
                               int* __restrict__ cursor, int* __restrict__ out, int E, int n) {
  int e = blockIdx.x * blockDim.x + threadIdx.x;
  if (e >= E + n) return;
  int s = (e < E) ? src[e] : (e - E);
  int d = (e < E) ? dst[e] : (e - E);
  int pos = atomicAdd(&cursor[d], 1);
  out[pos] = s;
}

// ---------------- fp32 tiled GEMM: C[M,Nc] = A[M,K] @ B[K,Nc] ----------------
// 64x64 tile, BK=16, 256 threads, 4x4 per thread
__global__ __launch_bounds__(256) void gemm_kernel(const float* __restrict__ A,
                                                   const float* __restrict__ B,
                                                   float* __restrict__ C, int M, int K, int Nc) {
  __shared__ float As[16][68];  // [k][m], padded
  __shared__ float Bs[16][64];  // [k][n]
  int tid = threadIdx.x;
  int tx = tid & 15, ty = tid >> 4;
  int m0 = blockIdx.x * 64;
  int c0 = blockIdx.y * 64;
  float acc[4][4] = {};
  int am = tid >> 2;       // 0..63
  int ak = (tid & 3) * 4;  // 0,4,8,12
  int br0 = tid >> 6;      // 0..3
  int bc = tid & 63;

  for (int kb = 0; kb < K; kb += 16) {
    float4 av = make_float4(0.f, 0.f, 0.f, 0.f);
    int arow = m0 + am;
    if (arow < M) av = *(const float4*)&A[arow * K + kb + ak];
    As[ak + 0][am] = av.x;
    As[ak + 1][am] = av.y;
    As[ak + 2][am] = av.z;
    As[ak + 3][am] = av.w;
#pragma unroll
    for (int t = 0; t < 4; t++) {
      int r = t * 4 + br0;
      Bs[r][bc] = B[(kb + r) * Nc + c0 + bc];
    }
    __syncthreads();
#pragma unroll
    for (int k = 0; k < 16; k++) {
      float4 a = *(const float4*)&As[k][ty * 4];
      float4 b = *(const float4*)&Bs[k][tx * 4];
      acc[0][0] += a.x * b.x; acc[0][1] += a.x * b.y; acc[0][2] += a.x * b.z; acc[0][3] += a.x * b.w;
      acc[1][0] += a.y * b.x; acc[1][1] += a.y * b.y; acc[1][2] += a.y * b.z; acc[1][3] += a.y * b.w;
      acc[2][0] += a.z * b.x; acc[2][1] += a.z * b.y; acc[2][2] += a.z * b.z; acc[2][3] += a.z * b.w;
      acc[3][0] += a.w * b.x; acc[3][1] += a.w * b.y; acc[3][2] += a.w * b.z; acc[3][3] += a.w * b.w;
    }
    __syncthreads();
  }
#pragma unroll
  for (int i = 0; i < 4; i++) {
    int row = m0 + ty * 4 + i;
    if (row < M) {
      float4 r = make_float4(acc[i][0], acc[i][1], acc[i][2], acc[i][3]);
      *(float4*)&C[row * Nc + c0 + tx * 4] = r;
    }
  }
}

// ---------------- per-node attention scores: es/ed[i][h] = sum_c h[i][h*64+c]*a[h][c] ----------------
__global__ void scores_kernel(const float* __restrict__ h, const float* __restrict__ a_src,
                              const float* __restrict__ a_dst, float* __restrict__ es,
                              float* __restrict__ ed, int H) {
  int i = blockIdx.x;
  int c = threadIdx.x;  // blockDim = H*64
  int head = c >> 6;
  int lane = c & 63;
  float v = h[i * (H * 64) + c];
  float ps = v * a_src[c];
  float pd = v * a_dst[c];
  for (int o = 32; o > 0; o >>= 1) {
    ps += __shfl_down(ps, o);
    pd += __shfl_down(pd, o);
  }
  if (lane == 0) {
    es[i * H + head] = ps;
    ed[i * H + head] = pd;
  }
}

// ---------------- per-dst online softmax stats (max, sum) ----------------
template <int H>
__global__ void stats_kernel(const int* __restrict__ offsets, const int* __restrict__ src_sorted,
                             const float* __restrict__ es, const float* __restrict__ ed,
                             float* __restrict__ m_out, float* __restrict__ s_out, int n) {
  int node = blockIdx.x * (blockDim.x >> 6) + (threadIdx.x >> 6);
  int lane = threadIdx.x & 63;
  if (node >= n) return;
  int off = offsets[node];
  int deg = offsets[node + 1] - off;
  float m[H], s[H], edv[H];
#pragma unroll
  for (int h = 0; h < H; h++) {
    m[h] = -INFINITY;
    s[h] = 0.f;
    edv[h] = ed[node * H + h];
  }
  for (int j = lane; j < deg; j += 64) {
    int sidx = src_sorted[off + j];
#pragma unroll
    for (int h = 0; h < H; h++) {
      float e = lrelu(es[sidx * H + h] + edv[h]);
      if (e > m[h]) {
        s[h] = s[h] * __expf(m[h] - e) + 1.f;  // exp(-inf)=0 handles first element
        m[h] = e;
      } else {
        s[h] += __expf(e - m[h]);
      }
    }
  }
  for (int o = 32; o > 0; o >>= 1) {
#pragma unroll
    for (int h = 0; h < H; h++) {
      float mo = __shfl_down(m[h], o);
      float so = __shfl_down(s[h], o);
      float M = fmaxf(m[h], mo);
      float sn = 0.f;
      if (m[h] > -INFINITY) sn += s[h] * __expf(m[h] - M);
      if (mo > -INFINITY) sn += so * __expf(mo - M);
      m[h] = M;
      s[h] = sn;
    }
  }
  if (lane == 0) {
#pragma unroll
    for (int h = 0; h < H; h++) {
      m_out[node * H + h] = m[h];
      s_out[node * H + h] = s[h];
    }
  }
}

// ---------------- per-dst aggregation: out[i] = sum_e alpha_e * h[src_e] (+bias, opt relu) -------
template <int HC, int H, bool RELU>
__global__ void aggregate_kernel(const float* __restrict__ h, const int* __restrict__ offsets,
                                 const int* __restrict__ src_sorted, const float* __restrict__ es,
                                 const float* __restrict__ ed, const float* __restrict__ m_arr,
                                 const float* __restrict__ s_arr, const float* __restrict__ bias,
                                 float* __restrict__ out, int n) {
  int node = blockIdx.x * (blockDim.x >> 6) + (threadIdx.x >> 6);
  int lane = threadIdx.x & 63;
  if (node >= n) return;
  constexpr int CPL = HC / 64;  // channels per lane: 4 (HC=256) or 1 (HC=64)
  int head = (lane * CPL) >> 6;
  float myEd = ed[node * H + head];
  float myM = m_arr[node * H + head];
  float invS = 1.0f / (s_arr[node * H + head] + 1e-16f);
  int off = offsets[node];
  int deg = offsets[node + 1] - off;
  if constexpr (CPL == 4) {
    float4 acc = make_float4(0.f, 0.f, 0.f, 0.f);
    for (int j = 0; j < deg; ++j) {
      int sidx = src_sorted[off + j];
      float e = lrelu(es[sidx * H + head] + myEd);
      float w = __expf(e - myM) * invS;
      float4 v = ((const float4*)h)[sidx * 64 + lane];
      acc.x += w * v.x;
      acc.y += w * v.y;
      acc.z += w * v.z;
      acc.w += w * v.w;
    }
    float4 b = ((const float4*)bias)[lane];
    acc.x += b.x; acc.y += b.y; acc.z += b.z; acc.w += b.w;
    if (RELU) {
      acc.x = fmaxf(acc.x, 0.f); acc.y = fmaxf(acc.y, 0.f);
      acc.z = fmaxf(acc.z, 0.f); acc.w = fmaxf(acc.w, 0.f);
    }
    ((float4*)out)[node * 64 + lane] = acc;
  } else {
    float acc = 0.f;
    for (int j = 0; j < deg; ++j) {
      int sidx = src_sorted[off + j];
      float e = lrelu(es[sidx * H + head] + myEd);
      float w = __expf(e - myM) * invS;
      acc += w * h[sidx * 64 + lane];
    }
    acc += bias[lane];
    if (RELU) acc = fmaxf(acc, 0.f);
    out[node * 64 + lane] = acc;
  }
}

// ---------------- global mean pool (batch is sorted) ----------------
#define POOL_CHUNK 128
__global__ void pool_kernel(const float* __restrict__ h, const int* __restrict__ batch,
                            float* __restrict__ pool, float* __restrict__ cnt, int n) {
  int c = threadIdx.x;  // 64
  int start = blockIdx.x * POOL_CHUNK;
  int end = min(start + POOL_CHUNK, n);
  if (start >= end) return;
  float acc = 0.f;
  int curg = batch[start];
  int runcnt = 0;
  for (int i = start; i < end; i++) {
    int g = batch[i];
    if (g != curg) {
      atomicAdd(&pool[curg * 64 + c], acc);
      if (c == 0) atomicAdd(&cnt[curg], (float)runcnt);
      acc = 0.f;
      runcnt = 0;
      curg = g;
    }
    acc += h[i * 64 + c];
    runcnt++;
  }
  atomicAdd(&pool[curg * 64 + c], acc);
  if (c == 0) atomicAdd(&cnt[curg], (float)runcnt);
}

__global__ void final_kernel(const float* __restrict__ pool, const float* __restrict__ cnt,
                             const float* __restrict__ lin_w, const float* __restrict__ lin_b,
                             float* __restrict__ out) {
  int g = blockIdx.x;
  int c = threadIdx.x;  // 64
  float denom = fmaxf(cnt[g], 1.0f);
  float v = pool[g * 64 + c] / denom * lin_w[c];
  for (int o = 32; o > 0; o >>= 1) v += __shfl_down(v, o);
  if (c == 0) out[g] = v + lin_b[0];
}

extern "C" void kernel_launch(void* const* d_in, const int* in_sizes, int n_in, void* d_out,
                              int out_size, void* d_ws, size_t ws_size, hipStream_t stream) {
  const float* x = (const float*)d_in[0];
  const int* edge_index = (const int*)d_in[1];
  const int* batch = (const int*)d_in[2];
  const float* W0 = (const float*)d_in[3];
  const float* a_src0 = (const float*)d_in[4];
  const float* a_dst0 = (const float*)d_in[5];
  const float* b0 = (const float*)d_in[6];
  const float* W1 = (const float*)d_in[7];
  const float* a_src1 = (const float*)d_in[8];
  const float* a_dst1 = (const float*)d_in[9];
  const float* b1 = (const float*)d_in[10];
  const float* W2 = (const float*)d_in[11];
  const float* a_src2 = (const float*)d_in[12];
  const float* a_dst2 = (const float*)d_in[13];
  const float* b2 = (const float*)d_in[14];
  const float* lin_w = (const float*)d_in[15];
  const float* lin_b = (const float*)d_in[16];
  float* out = (float*)d_out;

  const int N = in_sizes[2];      // 50000
  const int E = in_sizes[1] / 2;  // 800000
  const int EE = E + N;
  const int G = 64;
  const int FIN = in_sizes[0] / N;  // 128

  const int* srcArr = edge_index;
  const int* dstArr = edge_index + E;

  // workspace carve (256B aligned)
  size_t off = 0;
  auto alloc = [&](size_t bytes) -> void* {
    off = (off + 255) & ~(size_t)255;
    void* p = (char*)d_ws + off;
    off += bytes;
    return p;
  };
  float* bufA = (float*)alloc((size_t)N * 256 * 4);
  float* bufB = (float*)alloc((size_t)N * 256 * 4);
  float* es = (float*)alloc((size_t)N * 4 * 4);
  float* ed = (float*)alloc((size_t)N * 4 * 4);
  float* m_arr = (float*)alloc((size_t)N * 4 * 4);
  float* s_arr = (float*)alloc((size_t)N * 4 * 4);
  int* offsets = (int*)alloc((size_t)(N + 1) * 4);
  int* cursor = (int*)alloc((size_t)N * 4);
  int* src_sorted = (int*)alloc((size_t)EE * 4);
  float* pool = (float*)alloc((size_t)G * 64 * 4);
  float* cntArr = (float*)alloc((size_t)G * 4);
  (void)ws_size;

  // ---- CSR build ----
  hipMemsetAsync(cursor, 0, (size_t)N * 4, stream);
  int eb = (EE + 255) / 256;
  count_kernel<<<eb, 256, 0, stream>>>(dstArr, cursor, E, N);
  scan_kernel<<<1, 1024, 0, stream>>>(cursor, offsets, N);
  copy_kernel<<<(N + 255) / 256, 256, 0, stream>>>(offsets, cursor, N);
  scatter_kernel<<<eb, 256, 0, stream>>>(srcArr, dstArr, cursor, src_sorted, E, N);

  int nwb = (N + 3) / 4;  // blocks of 4 waves, one node per wave

  // ---- layer 0: 128 -> 4x64 concat, relu ----
  gemm_kernel<<<dim3((N + 63) / 64, 4), 256, 0, stream>>>(x, W0, bufA, N, FIN, 256);
  scores_kernel<<<N, 256, 0, stream>>>(bufA, a_src0, a_dst0, es, ed, 4);
  stats_kernel<4><<<nwb, 256, 0, stream>>>(offsets, src_sorted, es, ed, m_arr, s_arr, N);
  aggregate_kernel<256, 4, true>
      <<<nwb, 256, 0, stream>>>(bufA, offsets, src_sorted, es, ed, m_arr, s_arr, b0, bufB, N);

  // ---- layer 1: 256 -> 4x64 concat, relu ----
  gemm_kernel<<<dim3((N + 63) / 64, 4), 256, 0, stream>>>(bufB, W1, bufA, N, 256, 256);
  scores_kernel<<<N, 256, 0, stream>>>(bufA, a_src1, a_dst1, es, ed, 4);
  stats_kernel<4><<<nwb, 256, 0, stream>>>(offsets, src_sorted, es, ed, m_arr, s_arr, N);
  aggregate_kernel<256, 4, true>
      <<<nwb, 256, 0, stream>>>(bufA, offsets, src_sorted, es, ed, m_arr, s_arr, b1, bufB, N);

  // ---- layer 2: 256 -> 1x64, no relu ----
  gemm_kernel<<<dim3((N + 63) / 64, 1), 256, 0, stream>>>(bufB, W2, bufA, N, 256, 64);
  scores_kernel<<<N, 64, 0, stream>>>(bufA, a_src2, a_dst2, es, ed, 1);
  stats_kernel<1><<<nwb, 256, 0, stream>>>(offsets, src_sorted, es, ed, m_arr, s_arr, N);
  aggregate_kernel<64, 1, false>
      <<<nwb, 256, 0, stream>>>(bufA, offsets, src_sorted, es, ed, m_arr, s_arr, b2, bufB, N);

  // ---- global mean pool + linear ----
  hipMemsetAsync(pool, 0, (size_t)G * 64 * 4, stream);
  hipMemsetAsync(cntArr, 0, (size_t)G * 4, stream);
  pool_kernel<<<(N + POOL_CHUNK - 1) / POOL_CHUNK, 64, 0, stream>>>(bufB, batch, pool, cntArr, N);
  final_kernel<<<G, 64, 0, stream>>>(pool, cntArr, lin_w, lin_b, out);
}